// Round 3
// baseline (426.740 us; speedup 1.0000x reference)
//
#include <hip/hip_runtime.h>

// Problem constants (match reference)
constexpr int NUM_CLASSES  = 100000;
constexpr int EMBED_DIM    = 512;
constexpr int BATCH        = 16384;
constexpr int CENTER_ELEMS = NUM_CLASSES * EMBED_DIM;   // 51,200,000
constexpr int NSLOTS       = 256;                        // loss partial slots
constexpr int KMAX         = 8;                          // per-class item list capacity
constexpr float UPDATE_SCALE = 0.05f;                    // (1 - ALPHA)
constexpr float INV_COUNT  = 1.0f / 8388608.0f;          // 1/(BATCH*EMBED_DIM) = 2^-23

typedef float f4 __attribute__((ext_vector_type(4)));

// ---------------- workspace layout (int units from base) ----------------
// counts[NC] | items[NC*KMAX] | touched[BATCH] | ntouched[16] | partials[NSLOTS]
constexpr size_t WS_COUNTS_OFF  = 0;
constexpr size_t WS_ITEMS_OFF   = WS_COUNTS_OFF + (size_t)NUM_CLASSES;
constexpr size_t WS_TOUCHED_OFF = WS_ITEMS_OFF + (size_t)NUM_CLASSES * KMAX;
constexpr size_t WS_NTOUCH_OFF  = WS_TOUCHED_OFF + (size_t)BATCH;
constexpr size_t WS_PART_OFF    = WS_NTOUCH_OFF + 16;
constexpr size_t WS_NEW         = (WS_PART_OFF + NSLOTS) * 4;

__global__ void zero_ws_kernel(int* __restrict__ counts,
                               int* __restrict__ ntouched,
                               float* __restrict__ partials) {
    int g = blockIdx.x * blockDim.x + threadIdx.x;
    if (g < NUM_CLASSES) counts[g] = 0;
    if (g == 0) *ntouched = 0;
    if (g < NSLOTS) partials[g] = 0.0f;
}

// histogram + per-class item list + compacted touched-class list
__global__ void hist_kernel(const int* __restrict__ labels,
                            int* __restrict__ counts,
                            int* __restrict__ items,
                            int* __restrict__ touched,
                            int* __restrict__ ntouched) {
    int b = blockIdx.x * blockDim.x + threadIdx.x;
    if (b < BATCH) {
        int l = labels[b];
        int r = atomicAdd(&counts[l], 1);
        if (r < KMAX) items[l * KMAX + r] = b;
        if (r == 0) {
            int s = atomicAdd(ntouched, 1);
            touched[s] = l;
        }
    }
}

// Bulk stream: out[1+i] = centers[i] for all i. Grid-stride, deep MLP.
// Thread j writes aligned f4 out[4j..4j+3] = centers[4j-1..4j+2]. The source
// is 4B-aligned; build the f4 from two aligned loads (scalar + f4-neighbor
// reuse is avoided for simplicity: one dword + one dwordx4-1 pattern).
__global__ __launch_bounds__(256) void copy_shift_kernel(
        const float* __restrict__ src,
        float* __restrict__ out) {
    constexpr int NF4 = CENTER_ELEMS / 4;   // 12,800,000 f4-slots of out
    const int gid    = blockIdx.x * blockDim.x + threadIdx.x;
    const int stride = gridDim.x * blockDim.x;
    int j = gid;
    if (gid == 0) {
        out[1] = src[0];
        out[2] = src[1];
        out[3] = src[2];
        out[CENTER_ELEMS] = src[CENTER_ELEMS - 1];
        j = stride;                          // slot 0 handled above
    }
    for (; j < NF4; j += stride) {
        const float* p = src + 4 * j - 1;    // 4B-aligned
        f4 v;
        v.x = p[0];
        v.y = p[1];
        v.z = p[2];
        v.w = p[3];
        __builtin_nontemporal_store(v, (f4*)out + j);
    }
}

// One 128-thread block per touched class (compacted list). Applies the exact
// deterministic multi-item update, accumulates loss partial, rewrites the row
// (LDS shift -> aligned 16B stores). cnt>KMAX (P~2e-8) falls back to a full
// labels scan inline — correct, never taken for this data.
__global__ __launch_bounds__(128) void touched_update_kernel(
        const float* __restrict__ features,
        const int*   __restrict__ labels,
        const float* __restrict__ centers,
        const int*   __restrict__ counts,
        const int*   __restrict__ items,
        const int*   __restrict__ touched,
        const int*   __restrict__ ntouched,
        float* __restrict__ out,            // out[0]=loss, out+1 = new_centers
        float* __restrict__ partials) {
    const int nb = *ntouched;
    if (blockIdx.x >= nb) return;
    const int c   = touched[blockIdx.x];
    const int cnt = counts[c];
    const int t   = threadIdx.x;

    const f4 c4 = ((const f4*)(centers + (size_t)c * EMBED_DIM))[t];
    f4 s; s.x = 0.f; s.y = 0.f; s.z = 0.f; s.w = 0.f;
    float local = 0.0f;

    if (cnt <= KMAX) {
        for (int i = 0; i < cnt; ++i) {
            const int b = items[c * KMAX + i];
            const f4 f = ((const f4*)(features + (size_t)b * EMBED_DIM))[t];
            float dx = f.x - c4.x, dy = f.y - c4.y, dz = f.z - c4.z, dw = f.w - c4.w;
            s.x += dx; s.y += dy; s.z += dz; s.w += dw;
            local += dx * dx + dy * dy + dz * dz + dw * dw;
        }
    } else {
        for (int b = 0; b < BATCH; ++b) {
            if (labels[b] == c) {
                const f4 f = ((const f4*)(features + (size_t)b * EMBED_DIM))[t];
                float dx = f.x - c4.x, dy = f.y - c4.y, dz = f.z - c4.z, dw = f.w - c4.w;
                s.x += dx; s.y += dy; s.z += dz; s.w += dw;
                local += dx * dx + dy * dy + dz * dz + dw * dw;
            }
        }
    }

    f4 n4;
    n4.x = fmaf(UPDATE_SCALE, s.x, c4.x);
    n4.y = fmaf(UPDATE_SCALE, s.y, c4.y);
    n4.z = fmaf(UPDATE_SCALE, s.z, c4.z);
    n4.w = fmaf(UPDATE_SCALE, s.w, c4.w);

    #pragma unroll
    for (int off = 32; off > 0; off >>= 1)
        local += __shfl_down(local, off, 64);
    if ((t & 63) == 0)
        atomicAdd(&partials[(blockIdx.x * 2 + (t >> 6)) & (NSLOTS - 1)], local);

    __shared__ float row[EMBED_DIM];
    ((f4*)row)[t] = n4;
    __syncthreads();

    const size_t R = (size_t)c * EMBED_DIM;
    if (t < 127) {
        f4 o;
        o.x = row[4 * t + 3];
        o.y = row[4 * t + 4];
        o.z = row[4 * t + 5];
        o.w = row[4 * t + 6];
        ((f4*)(out + R + 4))[t] = o;
    } else {
        out[R + 1] = row[0];
        out[R + 2] = row[1];
        out[R + 3] = row[2];
        out[R + EMBED_DIM] = row[EMBED_DIM - 1];
    }
}

__global__ __launch_bounds__(64) void finalize_loss_kernel(
        const float* __restrict__ partials,
        float* __restrict__ out) {
    float v = 0.0f;
    #pragma unroll
    for (int k = 0; k < NSLOTS / 64; ++k)
        v += partials[threadIdx.x + k * 64];
    #pragma unroll
    for (int off = 32; off > 0; off >>= 1)
        v += __shfl_down(v, off, 64);
    if (threadIdx.x == 0)
        out[0] = v * INV_COUNT;
}

// ---------------- fallback path (proven correct, tiny ws) ----------------

__global__ void copy_centers_kernel(const float* __restrict__ src,
                                    float* __restrict__ dst,
                                    float* __restrict__ ws_partials) {
    int gid = blockIdx.x * blockDim.x + threadIdx.x;
    if (gid < NSLOTS) ws_partials[gid] = 0.0f;
    int stride = gridDim.x * blockDim.x;
    for (int i = gid; i < CENTER_ELEMS; i += stride) dst[i] = src[i];
}

__global__ __launch_bounds__(128) void update_kernel(
        const float* __restrict__ features,
        const int*   __restrict__ labels,
        const float* __restrict__ centers,
        float* __restrict__ out,
        float* __restrict__ ws_partials) {
    const int b = blockIdx.x;
    const int label = labels[b];
    const int t = threadIdx.x;
    const float4 f = ((const float4*)(features + (size_t)b * EMBED_DIM))[t];
    const float4 c = ((const float4*)(centers + (size_t)label * EMBED_DIM))[t];
    float4 d;
    d.x = f.x - c.x; d.y = f.y - c.y; d.z = f.z - c.z; d.w = f.w - c.w;
    float* nrow = out + 1 + (size_t)label * EMBED_DIM + (size_t)t * 4;
    atomicAdd(nrow + 0, UPDATE_SCALE * d.x);
    atomicAdd(nrow + 1, UPDATE_SCALE * d.y);
    atomicAdd(nrow + 2, UPDATE_SCALE * d.z);
    atomicAdd(nrow + 3, UPDATE_SCALE * d.w);
    float local = d.x * d.x + d.y * d.y + d.z * d.z + d.w * d.w;
    #pragma unroll
    for (int off = 32; off > 0; off >>= 1)
        local += __shfl_down(local, off, 64);
    if ((t & 63) == 0)
        atomicAdd(&ws_partials[(b * 2 + (t >> 6)) & (NSLOTS - 1)], local);
}

// ---------------- launcher ----------------

extern "C" void kernel_launch(void* const* d_in, const int* in_sizes, int n_in,
                              void* d_out, int out_size, void* d_ws, size_t ws_size,
                              hipStream_t stream) {
    const float* features = (const float*)d_in[0];
    const int*   labels   = (const int*)d_in[1];
    const float* centers  = (const float*)d_in[2];
    float* out = (float*)d_out;

    if (ws_size >= WS_NEW) {
        int* wsi       = (int*)d_ws;
        int* counts    = wsi + WS_COUNTS_OFF;
        int* items     = wsi + WS_ITEMS_OFF;
        int* touched   = wsi + WS_TOUCHED_OFF;
        int* ntouched  = wsi + WS_NTOUCH_OFF;
        float* partials = (float*)(wsi + WS_PART_OFF);

        zero_ws_kernel<<<(NUM_CLASSES + 255) / 256, 256, 0, stream>>>(
            counts, ntouched, partials);
        hist_kernel<<<(BATCH + 255) / 256, 256, 0, stream>>>(
            labels, counts, items, touched, ntouched);
        copy_shift_kernel<<<2048, 256, 0, stream>>>(centers, out);
        touched_update_kernel<<<BATCH, 128, 0, stream>>>(
            features, labels, centers, counts, items, touched, ntouched,
            out, partials);
        finalize_loss_kernel<<<1, 64, 0, stream>>>(partials, out);
    } else {
        float* partials = (float*)d_ws;
        copy_centers_kernel<<<8192, 256, 0, stream>>>(centers, out + 1, partials);
        update_kernel<<<BATCH, 128, 0, stream>>>(features, labels, centers, out, partials);
        finalize_loss_kernel<<<1, 64, 0, stream>>>(partials, out);
    }
}

// Round 4
// 407.794 us; speedup vs baseline: 1.0465x; 1.0465x over previous
//
#include <hip/hip_runtime.h>

// Problem constants (match reference)
constexpr int NUM_CLASSES  = 100000;
constexpr int EMBED_DIM    = 512;
constexpr int BATCH        = 16384;
constexpr int CENTER_ELEMS = NUM_CLASSES * EMBED_DIM;   // 51,200,000
constexpr int NSLOTS       = 256;                        // loss partial slots
constexpr int KMAX         = 8;                          // per-class item list capacity
constexpr float UPDATE_SCALE = 0.05f;                    // (1 - ALPHA)
constexpr float INV_COUNT  = 1.0f / 8388608.0f;          // 1/(BATCH*EMBED_DIM) = 2^-23

typedef float f4 __attribute__((ext_vector_type(4)));

// ---------------- workspace layout (int units from base) ----------------
// counts[NC] | items[NC*KMAX] | touched[BATCH] | ntouched[16] | partials[NSLOTS]
constexpr size_t WS_COUNTS_OFF  = 0;
constexpr size_t WS_ITEMS_OFF   = WS_COUNTS_OFF + (size_t)NUM_CLASSES;
constexpr size_t WS_TOUCHED_OFF = WS_ITEMS_OFF + (size_t)NUM_CLASSES * KMAX;
constexpr size_t WS_NTOUCH_OFF  = WS_TOUCHED_OFF + (size_t)BATCH;
constexpr size_t WS_PART_OFF    = WS_NTOUCH_OFF + 16;
constexpr size_t WS_NEW         = (WS_PART_OFF + NSLOTS) * 4;

__global__ void zero_ws_kernel(int* __restrict__ counts,
                               int* __restrict__ ntouched,
                               float* __restrict__ partials) {
    int g = blockIdx.x * blockDim.x + threadIdx.x;
    if (g < NUM_CLASSES) counts[g] = 0;
    if (g == 0) *ntouched = 0;
    if (g < NSLOTS) partials[g] = 0.0f;
}

// histogram + per-class item list + compacted touched-class list
__global__ void hist_kernel(const int* __restrict__ labels,
                            int* __restrict__ counts,
                            int* __restrict__ items,
                            int* __restrict__ touched,
                            int* __restrict__ ntouched) {
    int b = blockIdx.x * blockDim.x + threadIdx.x;
    if (b < BATCH) {
        int l = labels[b];
        int r = atomicAdd(&counts[l], 1);
        if (r < KMAX) items[l * KMAX + r] = b;
        if (r == 0) {
            int s = atomicAdd(ntouched, 1);
            touched[s] = l;
        }
    }
}

// Bulk stream: out[1+i] = centers[i]. Mirror of the proven 6.3 TB/s copy:
// ALIGNED f4 load + ALIGNED PLAIN f4 store. The +1-float shift is done in
// registers: out-slot j = (src[4j-1], src[4j], src[4j+1], src[4j+2]); the
// first component is the previous lane's w (shfl_up by 1); lane 0 of each
// wave loads src[4j-1] directly. Consecutive lanes hold consecutive j, and
// partially-active tail waves keep a lane prefix, so the shuffle is exact.
__global__ __launch_bounds__(256) void copy_shift_kernel(
        const float* __restrict__ src,
        float* __restrict__ out) {
    constexpr int NF4 = CENTER_ELEMS / 4;   // 12,800,000 f4-slots
    const int gid    = blockIdx.x * blockDim.x + threadIdx.x;
    const int stride = gridDim.x * blockDim.x;
    const int lane   = threadIdx.x & 63;
    for (int j = gid; j < NF4; j += stride) {
        f4 v = ((const f4*)src)[j];                       // aligned 16B load
        float wprev = __shfl_up(v.w, 1, 64);
        if (lane == 0 && j > 0) wprev = src[4 * j - 1];
        if (j == 0) {
            // out[0] is the loss slot (written by finalize); shift edges:
            out[1] = v.x;
            out[2] = v.y;
            out[3] = v.z;
            out[CENTER_ELEMS] = src[CENTER_ELEMS - 1];
        } else {
            f4 o;
            o.x = wprev; o.y = v.x; o.z = v.y; o.w = v.z;
            ((f4*)out)[j] = o;                            // aligned 16B store
        }
    }
}

// Two touched classes per 256-thread block (independent half-blocks) to halve
// block count and double resident MLP. Each half: exact deterministic
// multi-item update, loss partial, row rewrite via LDS shift -> aligned 16B
// stores. cnt>KMAX (P~2e-8) falls back to a full labels scan inline.
__global__ __launch_bounds__(256) void touched_update_kernel(
        const float* __restrict__ features,
        const int*   __restrict__ labels,
        const float* __restrict__ centers,
        const int*   __restrict__ counts,
        const int*   __restrict__ items,
        const int*   __restrict__ touched,
        const int*   __restrict__ ntouched,
        float* __restrict__ out,            // out[0]=loss, out+1 = new_centers
        float* __restrict__ partials) {
    const int nb   = *ntouched;
    const int t    = threadIdx.x;
    const int half = t >> 7;                 // 0 or 1
    const int ts   = t & 127;
    const int idx  = blockIdx.x * 2 + half;
    const bool active = idx < nb;

    __shared__ float row[2][EMBED_DIM];
    int c = 0;

    if (active) {
        c = touched[idx];
        const int cnt = counts[c];

        const f4 c4 = ((const f4*)(centers + (size_t)c * EMBED_DIM))[ts];
        f4 s; s.x = 0.f; s.y = 0.f; s.z = 0.f; s.w = 0.f;
        float local = 0.0f;

        if (cnt <= KMAX) {
            for (int i = 0; i < cnt; ++i) {
                const int b = items[c * KMAX + i];
                const f4 f = ((const f4*)(features + (size_t)b * EMBED_DIM))[ts];
                float dx = f.x - c4.x, dy = f.y - c4.y;
                float dz = f.z - c4.z, dw = f.w - c4.w;
                s.x += dx; s.y += dy; s.z += dz; s.w += dw;
                local += dx * dx + dy * dy + dz * dz + dw * dw;
            }
        } else {
            for (int b = 0; b < BATCH; ++b) {
                if (labels[b] == c) {
                    const f4 f = ((const f4*)(features + (size_t)b * EMBED_DIM))[ts];
                    float dx = f.x - c4.x, dy = f.y - c4.y;
                    float dz = f.z - c4.z, dw = f.w - c4.w;
                    s.x += dx; s.y += dy; s.z += dz; s.w += dw;
                    local += dx * dx + dy * dy + dz * dz + dw * dw;
                }
            }
        }

        f4 n4;
        n4.x = fmaf(UPDATE_SCALE, s.x, c4.x);
        n4.y = fmaf(UPDATE_SCALE, s.y, c4.y);
        n4.z = fmaf(UPDATE_SCALE, s.z, c4.z);
        n4.w = fmaf(UPDATE_SCALE, s.w, c4.w);

        #pragma unroll
        for (int off = 32; off > 0; off >>= 1)
            local += __shfl_down(local, off, 64);
        if ((t & 63) == 0)
            atomicAdd(&partials[(idx * 2 + (ts >> 6)) & (NSLOTS - 1)], local);

        ((f4*)row[half])[ts] = n4;
    }
    __syncthreads();

    if (active) {
        const size_t R = (size_t)c * EMBED_DIM;
        if (ts < 127) {
            f4 o;
            o.x = row[half][4 * ts + 3];
            o.y = row[half][4 * ts + 4];
            o.z = row[half][4 * ts + 5];
            o.w = row[half][4 * ts + 6];
            ((f4*)(out + R + 4))[ts] = o;
        } else {
            out[R + 1] = row[half][0];
            out[R + 2] = row[half][1];
            out[R + 3] = row[half][2];
            out[R + EMBED_DIM] = row[half][EMBED_DIM - 1];
        }
    }
}

__global__ __launch_bounds__(64) void finalize_loss_kernel(
        const float* __restrict__ partials,
        float* __restrict__ out) {
    float v = 0.0f;
    #pragma unroll
    for (int k = 0; k < NSLOTS / 64; ++k)
        v += partials[threadIdx.x + k * 64];
    #pragma unroll
    for (int off = 32; off > 0; off >>= 1)
        v += __shfl_down(v, off, 64);
    if (threadIdx.x == 0)
        out[0] = v * INV_COUNT;
}

// ---------------- fallback path (proven correct, tiny ws) ----------------

__global__ void copy_centers_kernel(const float* __restrict__ src,
                                    float* __restrict__ dst,
                                    float* __restrict__ ws_partials) {
    int gid = blockIdx.x * blockDim.x + threadIdx.x;
    if (gid < NSLOTS) ws_partials[gid] = 0.0f;
    int stride = gridDim.x * blockDim.x;
    for (int i = gid; i < CENTER_ELEMS; i += stride) dst[i] = src[i];
}

__global__ __launch_bounds__(128) void update_kernel(
        const float* __restrict__ features,
        const int*   __restrict__ labels,
        const float* __restrict__ centers,
        float* __restrict__ out,
        float* __restrict__ ws_partials) {
    const int b = blockIdx.x;
    const int label = labels[b];
    const int t = threadIdx.x;
    const float4 f = ((const float4*)(features + (size_t)b * EMBED_DIM))[t];
    const float4 c = ((const float4*)(centers + (size_t)label * EMBED_DIM))[t];
    float4 d;
    d.x = f.x - c.x; d.y = f.y - c.y; d.z = f.z - c.z; d.w = f.w - c.w;
    float* nrow = out + 1 + (size_t)label * EMBED_DIM + (size_t)t * 4;
    atomicAdd(nrow + 0, UPDATE_SCALE * d.x);
    atomicAdd(nrow + 1, UPDATE_SCALE * d.y);
    atomicAdd(nrow + 2, UPDATE_SCALE * d.z);
    atomicAdd(nrow + 3, UPDATE_SCALE * d.w);
    float local = d.x * d.x + d.y * d.y + d.z * d.z + d.w * d.w;
    #pragma unroll
    for (int off = 32; off > 0; off >>= 1)
        local += __shfl_down(local, off, 64);
    if ((t & 63) == 0)
        atomicAdd(&ws_partials[(b * 2 + (t >> 6)) & (NSLOTS - 1)], local);
}

// ---------------- launcher ----------------

extern "C" void kernel_launch(void* const* d_in, const int* in_sizes, int n_in,
                              void* d_out, int out_size, void* d_ws, size_t ws_size,
                              hipStream_t stream) {
    const float* features = (const float*)d_in[0];
    const int*   labels   = (const int*)d_in[1];
    const float* centers  = (const float*)d_in[2];
    float* out = (float*)d_out;

    if (ws_size >= WS_NEW) {
        int* wsi       = (int*)d_ws;
        int* counts    = wsi + WS_COUNTS_OFF;
        int* items     = wsi + WS_ITEMS_OFF;
        int* touched   = wsi + WS_TOUCHED_OFF;
        int* ntouched  = wsi + WS_NTOUCH_OFF;
        float* partials = (float*)(wsi + WS_PART_OFF);

        zero_ws_kernel<<<(NUM_CLASSES + 255) / 256, 256, 0, stream>>>(
            counts, ntouched, partials);
        hist_kernel<<<(BATCH + 255) / 256, 256, 0, stream>>>(
            labels, counts, items, touched, ntouched);
        copy_shift_kernel<<<2048, 256, 0, stream>>>(centers, out);
        touched_update_kernel<<<(BATCH + 1) / 2, 256, 0, stream>>>(
            features, labels, centers, counts, items, touched, ntouched,
            out, partials);
        finalize_loss_kernel<<<1, 64, 0, stream>>>(partials, out);
    } else {
        float* partials = (float*)d_ws;
        copy_centers_kernel<<<8192, 256, 0, stream>>>(centers, out + 1, partials);
        update_kernel<<<BATCH, 128, 0, stream>>>(features, labels, centers, out, partials);
        finalize_loss_kernel<<<1, 64, 0, stream>>>(partials, out);
    }
}